// Round 1
// baseline (570.837 us; speedup 1.0000x reference)
//
#include <hip/hip_runtime.h>
#include <hip/hip_bf16.h>
#include <math.h>

#define N_  512
#define D_  384
#define H_  12
#define DK_ 32
#define P_  128

__global__ __launch_bounds__(384) void k_proj(
    const float* __restrict__ x1d, const float* __restrict__ pose_t,
    const float* __restrict__ pose_r,
    const float* __restrict__ w_sq, const float* __restrict__ w_sk,
    const float* __restrict__ w_sv, const float* __restrict__ w_pq,
    const float* __restrict__ w_pk, const float* __restrict__ w_pv,
    float* __restrict__ qs, float* __restrict__ kst, float* __restrict__ vs,
    float* __restrict__ qp, float* __restrict__ kpt, float* __restrict__ vp)
{
    __shared__ float xs[D_];
    __shared__ float qpr[144], kpr[144], vpr[288];
    __shared__ float Rsh[9], Tsh[3];
    const int i = blockIdx.x;
    const int t = threadIdx.x;

    xs[t] = x1d[i * D_ + t];
    if (t < 9) Rsh[t] = pose_r[i * 9 + t];
    if (t < 3) Tsh[t] = pose_t[i * 3 + t];
    __syncthreads();

    float aq = 0.f, ak = 0.f, av = 0.f;
    for (int d = 0; d < D_; ++d) {
        float x = xs[d];
        aq += x * w_sq[d * D_ + t];
        ak += x * w_sk[d * D_ + t];
        av += x * w_sv[d * D_ + t];
    }
    qs[i * D_ + t]  = aq;
    kst[t * N_ + i] = ak;
    vs[i * D_ + t]  = av;

    if (t < 144) {
        float a1 = 0.f, a2 = 0.f;
        for (int d = 0; d < D_; ++d) {
            float x = xs[d];
            a1 += x * w_pq[d * 144 + t];
            a2 += x * w_pk[d * 144 + t];
        }
        qpr[t] = a1; kpr[t] = a2;
    }
    if (t < 288) {
        float a3 = 0.f;
        for (int d = 0; d < D_; ++d) a3 += xs[d] * w_pv[d * 288 + t];
        vpr[t] = a3;
    }
    __syncthreads();

    if (t < 144) {
        int x3 = t % 3, base = t - x3;
        float gq = Rsh[0*3+x3]*qpr[base] + Rsh[1*3+x3]*qpr[base+1] + Rsh[2*3+x3]*qpr[base+2] + Tsh[x3];
        float gk = Rsh[0*3+x3]*kpr[base] + Rsh[1*3+x3]*kpr[base+1] + Rsh[2*3+x3]*kpr[base+2] + Tsh[x3];
        qp[i * 144 + t] = gq;
        kpt[t * N_ + i] = gk;
    }
    if (t < 288) {
        int x3 = t % 3, base = t - x3;
        float gv = Rsh[0*3+x3]*vpr[base] + Rsh[1*3+x3]*vpr[base+1] + Rsh[2*3+x3]*vpr[base+2] + Tsh[x3];
        vp[i * 288 + t] = gv;
    }
}

__global__ __launch_bounds__(256) void k_logits_sp(
    const float* __restrict__ qs, const float* __restrict__ kst,
    const float* __restrict__ qp, const float* __restrict__ kpt,
    const float* __restrict__ bias, const float* __restrict__ tpw,
    float* __restrict__ logits)
{
    const int h  = blockIdx.x / 128;
    const int i0 = (blockIdx.x % 128) * 4;
    const int t  = threadIdx.x;
    __shared__ float qsh[4][32];
    __shared__ float qph[4][12];
    if (t < 128) { int il = t / 32, c = t % 32; qsh[il][c] = qs[(i0+il) * D_ + h*32 + c]; }
    else if (t < 176) { int r = t - 128; int il = r / 12, c = r % 12; qph[il][c] = qp[(i0+il)*144 + h*12 + c]; }
    const float pwh = 0.13608276f * log1pf(expf(tpw[h]));
    const float scalar_w = 0.10206207f;
    __syncthreads();

    for (int jh = 0; jh < 2; ++jh) {
        int j = t + jh * 256;
        float kv[32];
        #pragma unroll
        for (int c = 0; c < 32; ++c) kv[c] = kst[(h*32 + c) * N_ + j];
        float kp[12];
        #pragma unroll
        for (int c = 0; c < 12; ++c) kp[c] = kpt[(h*12 + c) * N_ + j];

        #pragma unroll
        for (int il = 0; il < 4; ++il) {
            float s = 0.f;
            #pragma unroll
            for (int c = 0; c < 32; ++c) s += qsh[il][c] * kv[c];
            float dsum = 0.f;
            #pragma unroll
            for (int p = 0; p < 4; ++p) {
                float dx = qph[il][p*3+0] - kp[p*3+0];
                float dy = qph[il][p*3+1] - kp[p*3+1];
                float dz = qph[il][p*3+2] - kp[p*3+2];
                dsum += sqrtf(dx*dx + dy*dy + dz*dz);
            }
            float lg = scalar_w * s - 0.5f * pwh * dsum + bias[(i0+il) * N_ + j];
            logits[((size_t)(h * N_ + (i0+il))) * N_ + j] = lg;
        }
    }
}

__global__ __launch_bounds__(256) void k_logits_pair(
    const float* __restrict__ x2d, const float* __restrict__ w_pb,
    float* __restrict__ logits)
{
    __shared__ float4 wsh[384];
    const int t = threadIdx.x;
    for (int idx = t; idx < 384; idx += 256) wsh[idx] = ((const float4*)w_pb)[idx];
    __syncthreads();

    const int lq = t & 3;
    const int qd = t >> 2;
    const float pair_w = 0.57735027f;

    for (int L = 0; L < 2; ++L) {
        const size_t pair = (size_t)blockIdx.x * 128 + L * 64 + qd;
        const float4* xp = (const float4*)(x2d + pair * 128) + lq * 8;
        float4 xv[8];
        #pragma unroll
        for (int k = 0; k < 8; ++k) xv[k] = xp[k];

        float acc[12];
        #pragma unroll
        for (int h = 0; h < 12; ++h) acc[h] = 0.f;

        #pragma unroll
        for (int k = 0; k < 8; ++k) {
            float xs4[4] = {xv[k].x, xv[k].y, xv[k].z, xv[k].w};
            #pragma unroll
            for (int e = 0; e < 4; ++e) {
                int p = lq * 32 + k * 4 + e;
                float x = xs4[e];
                float4 w0 = wsh[p*3+0], w1 = wsh[p*3+1], w2 = wsh[p*3+2];
                acc[0] += x*w0.x; acc[1] += x*w0.y; acc[2]  += x*w0.z; acc[3]  += x*w0.w;
                acc[4] += x*w1.x; acc[5] += x*w1.y; acc[6]  += x*w1.z; acc[7]  += x*w1.w;
                acc[8] += x*w2.x; acc[9] += x*w2.y; acc[10] += x*w2.z; acc[11] += x*w2.w;
            }
        }
        #pragma unroll
        for (int h = 0; h < 12; ++h) {
            acc[h] += __shfl_xor(acc[h], 1, 64);
            acc[h] += __shfl_xor(acc[h], 2, 64);
        }
        if (lq == 0) {
            int i = (int)(pair >> 9), j = (int)(pair & 511);
            #pragma unroll
            for (int h = 0; h < 12; ++h) {
                size_t idx = ((size_t)(h * N_ + i)) * N_ + j;
                logits[idx] += pair_w * acc[h];
            }
        }
    }
}

__global__ __launch_bounds__(256) void k_softmax(float* __restrict__ logits)
{
    const int row = blockIdx.x;
    float* ptr = logits + (size_t)row * N_;
    const int t = threadIdx.x;
    __shared__ float red[256];

    float a = ptr[t], b = ptr[t + 256];
    red[t] = fmaxf(a, b);
    __syncthreads();
    for (int s = 128; s > 0; s >>= 1) {
        if (t < s) red[t] = fmaxf(red[t], red[t + s]);
        __syncthreads();
    }
    float m = red[0];
    __syncthreads();
    float ea = __expf(a - m), eb = __expf(b - m);
    red[t] = ea + eb;
    __syncthreads();
    for (int s = 128; s > 0; s >>= 1) {
        if (t < s) red[t] += red[t + s];
        __syncthreads();
    }
    float inv = 1.0f / red[0];
    ptr[t]       = ea * inv;
    ptr[t + 256] = eb * inv;
}

__global__ __launch_bounds__(256) void k_tmp(
    const float* __restrict__ attn, const float* __restrict__ x2d,
    float* __restrict__ tmp)
{
    const int i = blockIdx.x;
    const int t = threadIdx.x;
    __shared__ float4 at[N_][3];
    __shared__ float red[2][1536];

    for (int idx = t; idx < 12 * N_; idx += 256) {
        int h = idx / N_, j = idx % N_;
        ((float*)&at[j][h >> 2])[h & 3] = attn[((size_t)(h * N_ + i)) * N_ + j];
    }
    __syncthreads();

    const int p = t & 127, jh = t >> 7;
    float acc[12];
    #pragma unroll
    for (int h = 0; h < 12; ++h) acc[h] = 0.f;
    const float* xb = x2d + (size_t)i * N_ * P_;

    #pragma unroll 4
    for (int j = jh; j < N_; j += 2) {
        float x = xb[j * P_ + p];
        float4 a0 = at[j][0], a1 = at[j][1], a2 = at[j][2];
        acc[0] += a0.x*x; acc[1] += a0.y*x; acc[2]  += a0.z*x; acc[3]  += a0.w*x;
        acc[4] += a1.x*x; acc[5] += a1.y*x; acc[6]  += a1.z*x; acc[7]  += a1.w*x;
        acc[8] += a2.x*x; acc[9] += a2.y*x; acc[10] += a2.z*x; acc[11] += a2.w*x;
    }
    #pragma unroll
    for (int h = 0; h < 12; ++h) red[jh][h * 128 + p] = acc[h];
    __syncthreads();
    for (int idx = t; idx < 1536; idx += 256)
        tmp[(size_t)i * 1536 + idx] = red[0][idx] + red[1][idx];
}

__global__ __launch_bounds__(256) void k_aggr_v(
    const float* __restrict__ attn, const float* __restrict__ vs,
    const float* __restrict__ vp, float* __restrict__ feat,
    float* __restrict__ outpg)
{
    const int h  = blockIdx.x / 128;
    const int i0 = (blockIdx.x % 128) * 4;
    const int t  = threadIdx.x;
    __shared__ float at[4][N_];
    for (int idx = t; idx < 4 * N_; idx += 256) {
        int il = idx / N_, j = idx % N_;
        at[il][j] = attn[((size_t)(h * N_ + i0 + il)) * N_ + j];
    }
    __syncthreads();

    const int vi = t & 63, ig = t >> 6;
    if (vi < 56) {
        const float* src;
        int stride;
        float* dst;
        if (vi < 32) {
            src = vs + h * 32 + vi; stride = D_;
            dst = feat + (size_t)(i0 + ig) * 1152 + h * 32 + vi;
        } else {
            int r = vi - 32;
            src = vp + h * 24 + r; stride = 288;
            dst = outpg + ((i0 + ig) * 12 + h) * 24 + r;
        }
        float acc = 0.f;
        #pragma unroll 4
        for (int j = 0; j < N_; ++j) acc += at[ig][j] * src[(size_t)j * stride];
        *dst = acc;
    }
}

__global__ __launch_bounds__(384) void k_feat(
    const float* __restrict__ tmp, const float* __restrict__ outpg,
    const float* __restrict__ pose_t, const float* __restrict__ pose_r,
    const float* __restrict__ w_pairv, float* __restrict__ feat)
{
    const int i = blockIdx.x;
    const int t = threadIdx.x;
    __shared__ float tsh[1536];
    __shared__ float pg[288];
    __shared__ float pl[288];
    __shared__ float Rsh[9], Tsh[3];

    for (int idx = t; idx < 1536; idx += 384) tsh[idx] = tmp[(size_t)i * 1536 + idx];
    if (t < 288) pg[t] = outpg[i * 288 + t];
    if (t < 9) Rsh[t] = pose_r[i * 9 + t];
    if (t < 3) Tsh[t] = pose_t[i * 3 + t];
    __syncthreads();

    {
        int h = t >> 5;
        const float* ts = tsh + h * 128;
        float acc = 0.f;
        #pragma unroll 4
        for (int p = 0; p < 128; ++p) acc += ts[p] * w_pairv[p * D_ + t];
        feat[(size_t)i * 1152 + 672 + t] = acc;
    }
    if (t < 288) {
        int x3 = t % 3, base = t - x3;
        float g0 = pg[base + 0] - Tsh[0];
        float g1 = pg[base + 1] - Tsh[1];
        float g2 = pg[base + 2] - Tsh[2];
        float v = Rsh[x3*3+0]*g0 + Rsh[x3*3+1]*g1 + Rsh[x3*3+2]*g2;
        pl[t] = v;
        feat[(size_t)i * 1152 + 384 + t] = v;
    }
    __syncthreads();
    if (t < 96) {
        float a = pl[t*3], b = pl[t*3+1], c = pl[t*3+2];
        feat[(size_t)i * 1152 + 1056 + t] = sqrtf(a*a + b*b + c*c);
    }
}

__global__ __launch_bounds__(384) void k_out(
    const float* __restrict__ feat, const float* __restrict__ w_out,
    const float* __restrict__ b_out, float* __restrict__ out)
{
    const int i0 = blockIdx.x * 4;
    const int t  = threadIdx.x;
    __shared__ float fsh[4][1152];
    for (int idx = t; idx < 4 * 1152; idx += 384)
        fsh[idx / 1152][idx % 1152] = feat[(size_t)i0 * 1152 + idx];
    __syncthreads();

    float acc0 = 0.f, acc1 = 0.f, acc2 = 0.f, acc3 = 0.f;
    #pragma unroll 4
    for (int k = 0; k < 1152; ++k) {
        float w = w_out[(size_t)k * D_ + t];
        acc0 += fsh[0][k] * w;
        acc1 += fsh[1][k] * w;
        acc2 += fsh[2][k] * w;
        acc3 += fsh[3][k] * w;
    }
    float b = b_out[t];
    out[(size_t)(i0 + 0) * D_ + t] = acc0 + b;
    out[(size_t)(i0 + 1) * D_ + t] = acc1 + b;
    out[(size_t)(i0 + 2) * D_ + t] = acc2 + b;
    out[(size_t)(i0 + 3) * D_ + t] = acc3 + b;
}

extern "C" void kernel_launch(void* const* d_in, const int* in_sizes, int n_in,
                              void* d_out, int out_size, void* d_ws, size_t ws_size,
                              hipStream_t stream)
{
    (void)in_sizes; (void)n_in; (void)out_size; (void)ws_size;
    const float* x1d     = (const float*)d_in[0];
    const float* x2d     = (const float*)d_in[1];
    const float* pose_t  = (const float*)d_in[2];
    const float* pose_r  = (const float*)d_in[3];
    const float* bias    = (const float*)d_in[4];
    const float* w_sq    = (const float*)d_in[5];
    const float* w_sk    = (const float*)d_in[6];
    const float* w_sv    = (const float*)d_in[7];
    const float* w_pb    = (const float*)d_in[8];
    const float* w_pq    = (const float*)d_in[9];
    const float* w_pk    = (const float*)d_in[10];
    const float* w_pv    = (const float*)d_in[11];
    const float* tpw     = (const float*)d_in[12];
    const float* w_pairv = (const float*)d_in[13];
    const float* w_out   = (const float*)d_in[14];
    const float* b_out   = (const float*)d_in[15];
    float* out = (float*)d_out;

    float* ws = (float*)d_ws;
    float* qs     = ws;
    float* kst    = qs     + 196608;
    float* vs     = kst    + 196608;
    float* qp     = vs     + 196608;
    float* kpt    = qp     + 73728;
    float* vp     = kpt    + 73728;
    float* logits = vp     + 147456;
    float* tmp    = logits + 3145728;
    float* outpg  = tmp    + 786432;
    float* feat   = outpg  + 147456;

    hipLaunchKernelGGL(k_proj, dim3(N_), dim3(384), 0, stream,
                       x1d, pose_t, pose_r, w_sq, w_sk, w_sv, w_pq, w_pk, w_pv,
                       qs, kst, vs, qp, kpt, vp);
    hipLaunchKernelGGL(k_logits_sp, dim3(12 * 128), dim3(256), 0, stream,
                       qs, kst, qp, kpt, bias, tpw, logits);
    hipLaunchKernelGGL(k_logits_pair, dim3(2048), dim3(256), 0, stream,
                       x2d, w_pb, logits);
    hipLaunchKernelGGL(k_softmax, dim3(12 * 512), dim3(256), 0, stream, logits);
    // logits now holds attn (softmax done in place)
    hipLaunchKernelGGL(k_tmp, dim3(N_), dim3(256), 0, stream, logits, x2d, tmp);
    hipLaunchKernelGGL(k_aggr_v, dim3(12 * 128), dim3(256), 0, stream,
                       logits, vs, vp, feat, outpg);
    hipLaunchKernelGGL(k_feat, dim3(N_), dim3(384), 0, stream,
                       tmp, outpg, pose_t, pose_r, w_pairv, feat);
    hipLaunchKernelGGL(k_out, dim3(N_ / 4), dim3(384), 0, stream,
                       feat, w_out, b_out, out);
}

// Round 2
// 439.064 us; speedup vs baseline: 1.3001x; 1.3001x over previous
//
#include <hip/hip_runtime.h>
#include <hip/hip_bf16.h>
#include <math.h>

#define N_  512
#define D_  384
#define H_  12
#define DK_ 32
#define P_  128

// ---------------------------------------------------------------------------
// K1: projections + affine. Grid (64, 5): blockIdx.x = i-group of 8 residues,
// blockIdx.y = segment {0:w_sq, 1:w_sk, 2:w_sv, 3:w_pq+w_pk, 4:w_pv}.
// x1d rows are read with wave-uniform addresses (-> s_load from scalar cache),
// weights with coalesced vector loads; each weight element amortized over 8 rows.
// ---------------------------------------------------------------------------
__global__ __launch_bounds__(384) void k_proj(
    const float* __restrict__ x1d, const float* __restrict__ pose_t,
    const float* __restrict__ pose_r,
    const float* __restrict__ w_sq, const float* __restrict__ w_sk,
    const float* __restrict__ w_sv, const float* __restrict__ w_pq,
    const float* __restrict__ w_pk, const float* __restrict__ w_pv,
    float* __restrict__ qs, float* __restrict__ kst, float* __restrict__ vs,
    float* __restrict__ qp, float* __restrict__ kpt, float* __restrict__ vp)
{
    const int seg = blockIdx.y;
    const int i0  = blockIdx.x * 8;
    const int t   = threadIdx.x;

    __shared__ float raw[8][288];
    __shared__ float Rsh[8][9];
    __shared__ float Tsh[8][3];

    if (seg < 3) {
        const float* __restrict__ w = (seg == 0) ? w_sq : (seg == 1) ? w_sk : w_sv;
        float acc[8];
        #pragma unroll
        for (int r = 0; r < 8; ++r) acc[r] = 0.f;
        for (int d = 0; d < D_; d += 4) {
            float4 xr[8];
            #pragma unroll
            for (int r = 0; r < 8; ++r)
                xr[r] = *(const float4*)(x1d + (i0 + r) * D_ + d);   // uniform -> s_load
            #pragma unroll
            for (int e = 0; e < 4; ++e) {
                float wv = w[(d + e) * D_ + t];
                #pragma unroll
                for (int r = 0; r < 8; ++r)
                    acc[r] += ((const float*)&xr[r])[e] * wv;
            }
        }
        if (seg == 0) {
            #pragma unroll
            for (int r = 0; r < 8; ++r) qs[(i0 + r) * D_ + t] = acc[r];
        } else if (seg == 1) {
            // transposed store: each thread owns 8 consecutive i -> 2x float4
            *(float4*)(kst + t * N_ + i0)     = make_float4(acc[0], acc[1], acc[2], acc[3]);
            *(float4*)(kst + t * N_ + i0 + 4) = make_float4(acc[4], acc[5], acc[6], acc[7]);
        } else {
            #pragma unroll
            for (int r = 0; r < 8; ++r) vs[(i0 + r) * D_ + t] = acc[r];
        }
    } else {
        // stage pose for 8 rows
        if (t < 72) Rsh[t / 9][t % 9] = pose_r[(i0 + t / 9) * 9 + t % 9];
        else if (t < 96) {
            int r = (t - 72) / 3, c = (t - 72) % 3;
            Tsh[r][c] = pose_t[(i0 + r) * 3 + c];
        }

        if (t < 288) {
            const float* __restrict__ w;
            int col, ldw;
            if (seg == 3) {
                if (t < 144) { w = w_pq; col = t;       ldw = 144; }
                else         { w = w_pk; col = t - 144; ldw = 144; }
            } else         { w = w_pv; col = t;       ldw = 288; }
            float acc[8];
            #pragma unroll
            for (int r = 0; r < 8; ++r) acc[r] = 0.f;
            for (int d = 0; d < D_; d += 4) {
                float4 xr[8];
                #pragma unroll
                for (int r = 0; r < 8; ++r)
                    xr[r] = *(const float4*)(x1d + (i0 + r) * D_ + d);
                #pragma unroll
                for (int e = 0; e < 4; ++e) {
                    float wv = w[(d + e) * ldw + col];
                    #pragma unroll
                    for (int r = 0; r < 8; ++r)
                        acc[r] += ((const float*)&xr[r])[e] * wv;
                }
            }
            #pragma unroll
            for (int r = 0; r < 8; ++r) raw[r][t] = acc[r];
        }
        __syncthreads();

        if (t < 288) {
            const int x3   = t % 3;
            const int base = t - x3;   // region offsets (0,144) divisible by 3
            if (seg == 3) {
                const int c = (t < 144) ? t : t - 144;
                if (t < 144) {
                    #pragma unroll
                    for (int r = 0; r < 8; ++r) {
                        float g = Rsh[r][0 + x3] * raw[r][base]
                                + Rsh[r][3 + x3] * raw[r][base + 1]
                                + Rsh[r][6 + x3] * raw[r][base + 2] + Tsh[r][x3];
                        qp[(i0 + r) * 144 + c] = g;
                    }
                } else {
                    float g[8];
                    #pragma unroll
                    for (int r = 0; r < 8; ++r)
                        g[r] = Rsh[r][0 + x3] * raw[r][base]
                             + Rsh[r][3 + x3] * raw[r][base + 1]
                             + Rsh[r][6 + x3] * raw[r][base + 2] + Tsh[r][x3];
                    *(float4*)(kpt + c * N_ + i0)     = make_float4(g[0], g[1], g[2], g[3]);
                    *(float4*)(kpt + c * N_ + i0 + 4) = make_float4(g[4], g[5], g[6], g[7]);
                }
            } else {
                #pragma unroll
                for (int r = 0; r < 8; ++r) {
                    float g = Rsh[r][0 + x3] * raw[r][base]
                            + Rsh[r][3 + x3] * raw[r][base + 1]
                            + Rsh[r][6 + x3] * raw[r][base + 2] + Tsh[r][x3];
                    vp[(i0 + r) * 288 + t] = g;
                }
            }
        }
    }
}

__global__ __launch_bounds__(256) void k_logits_sp(
    const float* __restrict__ qs, const float* __restrict__ kst,
    const float* __restrict__ qp, const float* __restrict__ kpt,
    const float* __restrict__ bias, const float* __restrict__ tpw,
    float* __restrict__ logits)
{
    const int h  = blockIdx.x / 128;
    const int i0 = (blockIdx.x % 128) * 4;
    const int t  = threadIdx.x;
    __shared__ float qsh[4][32];
    __shared__ float qph[4][12];
    if (t < 128) { int il = t / 32, c = t % 32; qsh[il][c] = qs[(i0+il) * D_ + h*32 + c]; }
    else if (t < 176) { int r = t - 128; int il = r / 12, c = r % 12; qph[il][c] = qp[(i0+il)*144 + h*12 + c]; }
    const float pwh = 0.13608276f * log1pf(expf(tpw[h]));
    const float scalar_w = 0.10206207f;
    __syncthreads();

    for (int jh = 0; jh < 2; ++jh) {
        int j = t + jh * 256;
        float kv[32];
        #pragma unroll
        for (int c = 0; c < 32; ++c) kv[c] = kst[(h*32 + c) * N_ + j];
        float kp[12];
        #pragma unroll
        for (int c = 0; c < 12; ++c) kp[c] = kpt[(h*12 + c) * N_ + j];

        #pragma unroll
        for (int il = 0; il < 4; ++il) {
            float s = 0.f;
            #pragma unroll
            for (int c = 0; c < 32; ++c) s += qsh[il][c] * kv[c];
            float dsum = 0.f;
            #pragma unroll
            for (int p = 0; p < 4; ++p) {
                float dx = qph[il][p*3+0] - kp[p*3+0];
                float dy = qph[il][p*3+1] - kp[p*3+1];
                float dz = qph[il][p*3+2] - kp[p*3+2];
                dsum += sqrtf(dx*dx + dy*dy + dz*dz);
            }
            float lg = scalar_w * s - 0.5f * pwh * dsum + bias[(i0+il) * N_ + j];
            logits[((size_t)(h * N_ + (i0+il))) * N_ + j] = lg;
        }
    }
}

__global__ __launch_bounds__(256) void k_logits_pair(
    const float* __restrict__ x2d, const float* __restrict__ w_pb,
    float* __restrict__ logits)
{
    __shared__ float4 wsh[384];
    const int t = threadIdx.x;
    for (int idx = t; idx < 384; idx += 256) wsh[idx] = ((const float4*)w_pb)[idx];
    __syncthreads();

    const int lq = t & 3;
    const int qd = t >> 2;
    const float pair_w = 0.57735027f;

    for (int L = 0; L < 2; ++L) {
        const size_t pair = (size_t)blockIdx.x * 128 + L * 64 + qd;
        const float4* xp = (const float4*)(x2d + pair * 128) + lq * 8;
        float4 xv[8];
        #pragma unroll
        for (int k = 0; k < 8; ++k) xv[k] = xp[k];

        float acc[12];
        #pragma unroll
        for (int h = 0; h < 12; ++h) acc[h] = 0.f;

        #pragma unroll
        for (int k = 0; k < 8; ++k) {
            float xs4[4] = {xv[k].x, xv[k].y, xv[k].z, xv[k].w};
            #pragma unroll
            for (int e = 0; e < 4; ++e) {
                int p = lq * 32 + k * 4 + e;
                float x = xs4[e];
                float4 w0 = wsh[p*3+0], w1 = wsh[p*3+1], w2 = wsh[p*3+2];
                acc[0] += x*w0.x; acc[1] += x*w0.y; acc[2]  += x*w0.z; acc[3]  += x*w0.w;
                acc[4] += x*w1.x; acc[5] += x*w1.y; acc[6]  += x*w1.z; acc[7]  += x*w1.w;
                acc[8] += x*w2.x; acc[9] += x*w2.y; acc[10] += x*w2.z; acc[11] += x*w2.w;
            }
        }
        #pragma unroll
        for (int h = 0; h < 12; ++h) {
            acc[h] += __shfl_xor(acc[h], 1, 64);
            acc[h] += __shfl_xor(acc[h], 2, 64);
        }
        if (lq == 0) {
            int i = (int)(pair >> 9), j = (int)(pair & 511);
            #pragma unroll
            for (int h = 0; h < 12; ++h) {
                size_t idx = ((size_t)(h * N_ + i)) * N_ + j;
                logits[idx] += pair_w * acc[h];
            }
        }
    }
}

__global__ __launch_bounds__(256) void k_softmax(float* __restrict__ logits)
{
    const int row = blockIdx.x;
    float* ptr = logits + (size_t)row * N_;
    const int t = threadIdx.x;
    __shared__ float red[256];

    float a = ptr[t], b = ptr[t + 256];
    red[t] = fmaxf(a, b);
    __syncthreads();
    for (int s = 128; s > 0; s >>= 1) {
        if (t < s) red[t] = fmaxf(red[t], red[t + s]);
        __syncthreads();
    }
    float m = red[0];
    __syncthreads();
    float ea = __expf(a - m), eb = __expf(b - m);
    red[t] = ea + eb;
    __syncthreads();
    for (int s = 128; s > 0; s >>= 1) {
        if (t < s) red[t] += red[t + s];
        __syncthreads();
    }
    float inv = 1.0f / red[0];
    ptr[t]       = ea * inv;
    ptr[t + 256] = eb * inv;
}

__global__ __launch_bounds__(256) void k_tmp(
    const float* __restrict__ attn, const float* __restrict__ x2d,
    float* __restrict__ tmp)
{
    const int i = blockIdx.x;
    const int t = threadIdx.x;
    __shared__ float4 at[N_][3];
    __shared__ float red[2][1536];

    for (int idx = t; idx < 12 * N_; idx += 256) {
        int h = idx / N_, j = idx % N_;
        ((float*)&at[j][h >> 2])[h & 3] = attn[((size_t)(h * N_ + i)) * N_ + j];
    }
    __syncthreads();

    const int p = t & 127, jh = t >> 7;
    float acc[12];
    #pragma unroll
    for (int h = 0; h < 12; ++h) acc[h] = 0.f;
    const float* xb = x2d + (size_t)i * N_ * P_;

    #pragma unroll 4
    for (int j = jh; j < N_; j += 2) {
        float x = xb[j * P_ + p];
        float4 a0 = at[j][0], a1 = at[j][1], a2 = at[j][2];
        acc[0] += a0.x*x; acc[1] += a0.y*x; acc[2]  += a0.z*x; acc[3]  += a0.w*x;
        acc[4] += a1.x*x; acc[5] += a1.y*x; acc[6]  += a1.z*x; acc[7]  += a1.w*x;
        acc[8] += a2.x*x; acc[9] += a2.y*x; acc[10] += a2.z*x; acc[11] += a2.w*x;
    }
    #pragma unroll
    for (int h = 0; h < 12; ++h) red[jh][h * 128 + p] = acc[h];
    __syncthreads();
    for (int idx = t; idx < 1536; idx += 256)
        tmp[(size_t)i * 1536 + idx] = red[0][idx] + red[1][idx];
}

__global__ __launch_bounds__(256) void k_aggr_v(
    const float* __restrict__ attn, const float* __restrict__ vs,
    const float* __restrict__ vp, float* __restrict__ feat,
    float* __restrict__ outpg)
{
    const int h  = blockIdx.x / 128;
    const int i0 = (blockIdx.x % 128) * 4;
    const int t  = threadIdx.x;
    __shared__ float at[4][N_];
    for (int idx = t; idx < 4 * N_; idx += 256) {
        int il = idx / N_, j = idx % N_;
        at[il][j] = attn[((size_t)(h * N_ + i0 + il)) * N_ + j];
    }
    __syncthreads();

    const int vi = t & 63, ig = t >> 6;
    if (vi < 56) {
        const float* src;
        int stride;
        float* dst;
        if (vi < 32) {
            src = vs + h * 32 + vi; stride = D_;
            dst = feat + (size_t)(i0 + ig) * 1152 + h * 32 + vi;
        } else {
            int r = vi - 32;
            src = vp + h * 24 + r; stride = 288;
            dst = outpg + ((i0 + ig) * 12 + h) * 24 + r;
        }
        float acc = 0.f;
        #pragma unroll 4
        for (int j = 0; j < N_; ++j) acc += at[ig][j] * src[(size_t)j * stride];
        *dst = acc;
    }
}

__global__ __launch_bounds__(384) void k_feat(
    const float* __restrict__ tmp, const float* __restrict__ outpg,
    const float* __restrict__ pose_t, const float* __restrict__ pose_r,
    const float* __restrict__ w_pairv, float* __restrict__ feat)
{
    const int i = blockIdx.x;
    const int t = threadIdx.x;
    __shared__ float tsh[1536];
    __shared__ float pg[288];
    __shared__ float pl[288];
    __shared__ float Rsh[9], Tsh[3];

    for (int idx = t; idx < 1536; idx += 384) tsh[idx] = tmp[(size_t)i * 1536 + idx];
    if (t < 288) pg[t] = outpg[i * 288 + t];
    if (t < 9) Rsh[t] = pose_r[i * 9 + t];
    if (t < 3) Tsh[t] = pose_t[i * 3 + t];
    __syncthreads();

    {
        int h = t >> 5;
        const float* ts = tsh + h * 128;
        float acc = 0.f;
        #pragma unroll 4
        for (int p = 0; p < 128; ++p) acc += ts[p] * w_pairv[p * D_ + t];
        feat[(size_t)i * 1152 + 672 + t] = acc;
    }
    if (t < 288) {
        int x3 = t % 3, base = t - x3;
        float g0 = pg[base + 0] - Tsh[0];
        float g1 = pg[base + 1] - Tsh[1];
        float g2 = pg[base + 2] - Tsh[2];
        float v = Rsh[x3*3+0]*g0 + Rsh[x3*3+1]*g1 + Rsh[x3*3+2]*g2;
        pl[t] = v;
        feat[(size_t)i * 1152 + 384 + t] = v;
    }
    __syncthreads();
    if (t < 96) {
        float a = pl[t*3], b = pl[t*3+1], c = pl[t*3+2];
        feat[(size_t)i * 1152 + 1056 + t] = sqrtf(a*a + b*b + c*c);
    }
}

// ---------------------------------------------------------------------------
// K6b: out partials. Grid 512 = 64 row-groups (8 rows) x 8 K-chunks (144).
// feat is read with wave-uniform addresses (scalar loads); w_out coalesced.
// ---------------------------------------------------------------------------
__global__ __launch_bounds__(384) void k_out_part(
    const float* __restrict__ feat, const float* __restrict__ w_out,
    float* __restrict__ part)
{
    const int kc = blockIdx.x >> 6;
    const int i0 = (blockIdx.x & 63) * 8;
    const int t  = threadIdx.x;
    const int k0 = kc * 144;

    float acc[8];
    #pragma unroll
    for (int r = 0; r < 8; ++r) acc[r] = 0.f;

    for (int d = 0; d < 144; d += 4) {
        float4 fr[8];
        #pragma unroll
        for (int r = 0; r < 8; ++r)
            fr[r] = *(const float4*)(feat + (size_t)(i0 + r) * 1152 + k0 + d);
        #pragma unroll
        for (int e = 0; e < 4; ++e) {
            float wv = w_out[(size_t)(k0 + d + e) * D_ + t];
            #pragma unroll
            for (int r = 0; r < 8; ++r)
                acc[r] += ((const float*)&fr[r])[e] * wv;
        }
    }
    #pragma unroll
    for (int r = 0; r < 8; ++r)
        part[((size_t)kc * N_ + i0 + r) * D_ + t] = acc[r];
}

__global__ __launch_bounds__(256) void k_out_red(
    const float* __restrict__ part, const float* __restrict__ b_out,
    float* __restrict__ out)
{
    const int idx = blockIdx.x * 256 + threadIdx.x;   // 0 .. 196607
    float s = b_out[idx % D_];
    #pragma unroll
    for (int kc = 0; kc < 8; ++kc) s += part[(size_t)kc * (N_ * D_) + idx];
    out[idx] = s;
}

extern "C" void kernel_launch(void* const* d_in, const int* in_sizes, int n_in,
                              void* d_out, int out_size, void* d_ws, size_t ws_size,
                              hipStream_t stream)
{
    (void)in_sizes; (void)n_in; (void)out_size; (void)ws_size;
    const float* x1d     = (const float*)d_in[0];
    const float* x2d     = (const float*)d_in[1];
    const float* pose_t  = (const float*)d_in[2];
    const float* pose_r  = (const float*)d_in[3];
    const float* bias    = (const float*)d_in[4];
    const float* w_sq    = (const float*)d_in[5];
    const float* w_sk    = (const float*)d_in[6];
    const float* w_sv    = (const float*)d_in[7];
    const float* w_pb    = (const float*)d_in[8];
    const float* w_pq    = (const float*)d_in[9];
    const float* w_pk    = (const float*)d_in[10];
    const float* w_pv    = (const float*)d_in[11];
    const float* tpw     = (const float*)d_in[12];
    const float* w_pairv = (const float*)d_in[13];
    const float* w_out   = (const float*)d_in[14];
    const float* b_out   = (const float*)d_in[15];
    float* out = (float*)d_out;

    float* ws = (float*)d_ws;
    float* qs     = ws;
    float* kst    = qs     + 196608;
    float* vs     = kst    + 196608;
    float* qp     = vs     + 196608;
    float* kpt    = qp     + 73728;
    float* vp     = kpt    + 73728;
    float* logits = vp     + 147456;
    float* tmp    = logits + 3145728;
    float* outpg  = tmp    + 786432;
    float* feat   = outpg  + 147456;
    float* part   = feat   + 589824;   // 8 * 512 * 384 = 1572864 floats

    hipLaunchKernelGGL(k_proj, dim3(64, 5), dim3(384), 0, stream,
                       x1d, pose_t, pose_r, w_sq, w_sk, w_sv, w_pq, w_pk, w_pv,
                       qs, kst, vs, qp, kpt, vp);
    hipLaunchKernelGGL(k_logits_sp, dim3(12 * 128), dim3(256), 0, stream,
                       qs, kst, qp, kpt, bias, tpw, logits);
    hipLaunchKernelGGL(k_logits_pair, dim3(2048), dim3(256), 0, stream,
                       x2d, w_pb, logits);
    hipLaunchKernelGGL(k_softmax, dim3(12 * 512), dim3(256), 0, stream, logits);
    // logits now holds attn (softmax done in place)
    hipLaunchKernelGGL(k_tmp, dim3(N_), dim3(256), 0, stream, logits, x2d, tmp);
    hipLaunchKernelGGL(k_aggr_v, dim3(12 * 128), dim3(256), 0, stream,
                       logits, vs, vp, feat, outpg);
    hipLaunchKernelGGL(k_feat, dim3(N_), dim3(384), 0, stream,
                       tmp, outpg, pose_t, pose_r, w_pairv, feat);
    hipLaunchKernelGGL(k_out_part, dim3(512), dim3(384), 0, stream,
                       feat, w_out, part);
    hipLaunchKernelGGL(k_out_red, dim3(768), dim3(256), 0, stream,
                       part, b_out, out);
}